// Round 21
// baseline (45.901 us; speedup 1.0000x reference)
//
#include <hip/hip_runtime.h>
#include <stdint.h>

// Problem constants (match reference)
#define BB 4
#define NN 16384
#define SS 4096
#define CC 64
#define KK 32

// 14-bit quantization (q = rintf(v*16383.f)); d2i exact int.
// Band +-27K around T (2.3x error margin) -> f64 recheck (proven R18..R20).
#define T_INT    10736108
#define LOW_INT  10709108
#define BAND_W   54000

// ws layout:
//   [0, 1MB)      packed float4 {x,y,z,0}
//   [1MB, 1.5MB)  qpts ushort4 {qx,qy,qz,0} (14-bit)
//   [3MB, 11MB)   featB bf16 [B][N][64] (128B rows)
#define PACKED_BYTES ((size_t)BB * NN * sizeof(float4))
#define IDX_BYTES    ((size_t)BB * SS * KK * sizeof(int))

typedef short short2v __attribute__((ext_vector_type(2)));

static __device__ __forceinline__ int mbcnt64(unsigned long long m) {
    return (int)__builtin_amdgcn_mbcnt_hi((unsigned)(m >> 32),
               __builtin_amdgcn_mbcnt_lo((unsigned)m, 0u));
}

#if __has_builtin(__builtin_amdgcn_sdot2)
static __device__ __forceinline__ int dot2i(short2v a, short2v b, int c) {
    return __builtin_amdgcn_sdot2(a, b, c, false);
}
#else
static __device__ __forceinline__ int dot2i(short2v a, short2v b, int c) {
    return (int)a.x * (int)b.x + (int)a.y * (int)b.y + c;   // bit-exact fallback
}
#endif

static __device__ __forceinline__ unsigned short f2bf(float f) {   // RNE
    unsigned u = __builtin_bit_cast(unsigned, f);
    return (unsigned short)((u + 0x7FFFu + ((u >> 16) & 1u)) >> 16);
}
static __device__ __forceinline__ float bf_lo(unsigned w) {
    return __builtin_bit_cast(float, w << 16);
}
static __device__ __forceinline__ float bf_hi(unsigned w) {
    return __builtin_bit_cast(float, w & 0xFFFF0000u);
}

// ---------------------------------------------------------------------------
// Kernel 0: prep = pack+quantize (blocks 0..63) + bf16 transpose (64..1087).
// ---------------------------------------------------------------------------
__global__ __launch_bounds__(256) void prep_kernel(const float* __restrict__ xyz,
                                                   const float* __restrict__ features,
                                                   float4* __restrict__ packed,
                                                   ushort4* __restrict__ qpts,
                                                   unsigned short* __restrict__ featB) {
    int blk = blockIdx.x;
    if (blk < 64) {
        for (int i = 0; i < 4; ++i) {
            int p = blk * 1024 + i * 256 + (int)threadIdx.x;
            float x = xyz[(size_t)p * 3 + 0];
            float y = xyz[(size_t)p * 3 + 1];
            float z = xyz[(size_t)p * 3 + 2];
            packed[p] = make_float4(x, y, z, 0.0f);
            ushort4 q;
            q.x = (unsigned short)rintf(x * 16383.0f);
            q.y = (unsigned short)rintf(y * 16383.0f);
            q.z = (unsigned short)rintf(z * 16383.0f);
            q.w = 0;
            qpts[p] = q;
        }
        return;
    }
    blk -= 64;
    int b  = blk >> 8;
    int n0 = (blk & 255) << 6;
    const float* f = features + (size_t)b * CC * NN;
    for (int i = 0; i < 4; ++i) {
        int e  = (int)threadIdx.x + i * 256;   // 0..1023
        int c4 = e & 15;
        int n  = n0 + (e >> 4);
        ushort4 v;
        v.x = f2bf(f[(size_t)(c4 * 4 + 0) * NN + n]);
        v.y = f2bf(f[(size_t)(c4 * 4 + 1) * NN + n]);
        v.z = f2bf(f[(size_t)(c4 * 4 + 2) * NN + n]);
        v.w = f2bf(f[(size_t)(c4 * 4 + 3) * NN + n]);
        *(ushort4*)(featB + ((size_t)b * NN + n) * 64 + c4 * 4) = v;   // 8B store
    }
}

// ---------------------------------------------------------------------------
// Kernel 1 (fused v21): 4 waves/block, each wave FULLY INDEPENDENT (its own
// centroid, its own LDS quarter, ZERO __syncthreads) — removes the
// max-of-4-scan-lengths retirement penalty while keeping v20's scan math
// (4 pts/lane/iter packed-i16, band -> f64 recheck; absmax-0.0 lineage) and
// 256B-wide stores. Intra-wave LDS ordering is compiler-handled (lgkmcnt).
// ---------------------------------------------------------------------------
__global__ __launch_bounds__(256) void fused_kernel(const float4* __restrict__ packed,
                                                    const ushort4* __restrict__ qpts,
                                                    const float* __restrict__ new_xyz,
                                                    const unsigned short* __restrict__ featB,
                                                    float* __restrict__ out) {
    __shared__ int   sidx[128];          // [w*32 + slot]
    __shared__ uint4 sfeat[4][32][8];    // 16KB; per-wave quarter, col=(c+row)&7

    int bid  = (int)blockIdx.x;
    int wgid = (bid & 7) * 512 + (bid >> 3);   // bijective: 4096 % 8 == 0
    int b  = wgid >> 10;
    int s0 = (wgid & 1023) << 2;
    int t  = (int)threadIdx.x;
    int w = t >> 6, lane = t & 63;
    int s = s0 + w;                      // this wave's centroid

    const float* nc = new_xyz + (size_t)(b * SS + s) * 3;
    const float nxf = nc[0], nyf = nc[1], nzf = nc[2];
    const int qcx = (int)rintf(nxf * 16383.0f);
    const int qcy = (int)rintf(nyf * 16383.0f);
    const int qcz = (int)rintf(nzf * 16383.0f);
    const short2v cxy2 = __builtin_bit_cast(short2v, (unsigned)((qcy << 16) | (qcx & 0xFFFF)));
    const short2v cz2  = __builtin_bit_cast(short2v, (unsigned)qcz);
    const double nx = (double)nxf, ny = (double)nyf, nz = (double)nzf;
    const double t1 = nx * nx + ny * ny + nz * nz;
    const double r2 = 0.2 * 0.2;

    const float4* pts = packed + (size_t)b * NN;
    const uint4*  qv  = (const uint4*)(qpts + (size_t)b * NN);  // 2 pts / uint4

#define TESTQ(WXY, WZ, J, INB)                                                  \
    {                                                                           \
        short2v dxy = __builtin_bit_cast(short2v, (WXY)) - cxy2;                \
        short2v dz2 = __builtin_bit_cast(short2v, (WZ))  - cz2;                 \
        int d2i = dot2i(dxy, dxy, dot2i(dz2, dz2, 0));                          \
        if ((unsigned)(d2i - LOW_INT) < (unsigned)BAND_W) {                     \
            float4 p = pts[J];                                                  \
            double pxd = (double)p.x, pyd = (double)p.y, pzd = (double)p.z;     \
            double t2d = pxd * pxd + pyd * pyd + pzd * pzd;                     \
            double dtd = nx * pxd + ny * pyd + nz * pzd;                        \
            INB = ((t1 + t2d) - 2.0 * dtd) < r2;                                \
        } else {                                                                \
            INB = d2i < T_INT;                                                  \
        }                                                                       \
    }

    // ---- Phase A: scan, 4 points/lane/iter, 1-iter prefetch (v20) ----
    int cnt = 0;
    int first = 0;
    uint4 u0 = qv[lane];
    uint4 u1 = qv[64 + lane];
    for (int i = 0; i < NN / 2; i += 128) {
        int nb = (i + 128 < NN / 2) ? (i + 128) : i;
        uint4 n0 = qv[nb + lane];
        uint4 n1 = qv[nb + 64 + lane];
        int base = i * 2;
        int jA = base + 2 * lane;
        int jC = base + 128 + 2 * lane;

        bool iA, iB, iC, iD;
        TESTQ(u0.x, u0.y, jA, iA)
        TESTQ(u0.z, u0.w, jA + 1, iB)
        TESTQ(u1.x, u1.y, jC, iC)
        TESTQ(u1.z, u1.w, jC + 1, iD)

        unsigned long long mA = __ballot(iA);
        unsigned long long mB = __ballot(iB);
        unsigned long long mC = __ballot(iC);
        unsigned long long mD = __ballot(iD);

        if (cnt == 0 && (mA | mB | mC | mD)) {
            if (mA | mB) {
                int cA = mA ? 2 * (int)__builtin_ctzll(mA)     : 0x7FFFFFFF;
                int cB = mB ? 2 * (int)__builtin_ctzll(mB) + 1 : 0x7FFFFFFF;
                first = base + (cA < cB ? cA : cB);
            } else {
                int cC = mC ? 2 * (int)__builtin_ctzll(mC)     : 0x7FFFFFFF;
                int cD = mD ? 2 * (int)__builtin_ctzll(mD) + 1 : 0x7FFFFFFF;
                first = base + 128 + (cC < cD ? cC : cD);
            }
        }
        int preAB = mbcnt64(mA) + mbcnt64(mB);
        int cAB   = (int)__popcll(mA) + (int)__popcll(mB);
        int preCD = mbcnt64(mC) + mbcnt64(mD);
        if (iA) { int sl = cnt + preAB;                      if (sl < KK) sidx[w * KK + sl] = jA; }
        if (iB) { int sl = cnt + preAB + (iA ? 1 : 0);       if (sl < KK) sidx[w * KK + sl] = jA + 1; }
        if (iC) { int sl = cnt + cAB + preCD;                if (sl < KK) sidx[w * KK + sl] = jC; }
        if (iD) { int sl = cnt + cAB + preCD + (iC ? 1 : 0); if (sl < KK) sidx[w * KK + sl] = jC + 1; }
        cnt += cAB + (int)__popcll(mC) + (int)__popcll(mD);
        if (cnt >= KK) break;
        u0 = n0; u1 = n1;
    }
#undef TESTQ
    if (lane >= cnt && lane < KK) sidx[w * KK + lane] = first;   // fill (0 if none)
    // no barrier: all subsequent LDS use is within this wave (lgkmcnt-ordered)

    const size_t cs = (size_t)SS * KK;
    size_t obase = (size_t)(b * 67) * cs + (size_t)s * KK;

    // ---- Phase B0: xyz channels (this wave's centroid only) ----
    if (lane < KK) {
        float4 p = pts[sidx[w * KK + lane]];
        size_t o = obase + lane;
        out[o]          = p.x - nxf;
        out[o + cs]     = p.y - nyf;
        out[o + 2 * cs] = p.z - nzf;
    }

    // ---- Phase B1: stage this wave's 32 bf16 rows (4KB), swizzled ----
    {
        int row = lane >> 1;                    // 0..31, 2 lanes/row
        int q   = lane & 1;                     // 64B half of the 128B row
        const uint4* src = (const uint4*)(featB +
            ((size_t)b * NN + sidx[w * KK + row]) * 64) + q * 4;
#pragma unroll
        for (int j = 0; j < 4; ++j)
            sfeat[w][row][(q * 4 + j + row) & 7] = src[j];
    }

    // ---- Phase B2: write 64 feature channels, 2 channels per store-instr ----
#pragma unroll
    for (int i = 0; i < 4; ++i) {
        int k  = lane & 31;
        int c8 = i * 2 + (lane >> 5);           // half-wave-uniform 0..7
        uint4 v = sfeat[w][k][(c8 + k) & 7];    // ds_read_b128 = 8 bf16
        float* pl = out + obase + (size_t)(3 + c8 * 8) * cs + k;
        pl[0]               = bf_lo(v.x);
        pl[cs]              = bf_hi(v.x);
        pl[2 * cs]          = bf_lo(v.y);
        pl[3 * cs]          = bf_hi(v.y);
        pl[4 * cs]          = bf_lo(v.z);
        pl[5 * cs]          = bf_hi(v.z);
        pl[6 * cs]          = bf_lo(v.w);
        pl[7 * cs]          = bf_hi(v.w);
    }
}

extern "C" void kernel_launch(void* const* d_in, const int* in_sizes, int n_in,
                              void* d_out, int out_size, void* d_ws, size_t ws_size,
                              hipStream_t stream) {
    const float* xyz      = (const float*)d_in[0];   // [B,N,3]
    const float* new_xyz  = (const float*)d_in[1];   // [B,S,3]
    const float* features = (const float*)d_in[2];   // [B,C,N]
    float* out = (float*)d_out;                      // [B,67,S,K]

    float4*         packed = (float4*)d_ws;
    ushort4*        qpts   = (ushort4*)((char*)d_ws + PACKED_BYTES);
    unsigned short* featB  = (unsigned short*)((char*)d_ws + PACKED_BYTES + IDX_BYTES);

    prep_kernel<<<64 + BB * (NN / 64), 256, 0, stream>>>(xyz, features, packed,
                                                         qpts, featB);
    fused_kernel<<<BB * SS / 4, 256, 0, stream>>>(packed, qpts, new_xyz, featB, out);
}